// Round 6
// baseline (855.279 us; speedup 1.0000x reference)
//
#include <hip/hip_runtime.h>
#include <math.h>

#define HID 150
#define EMB 300
#define NNODES 8191
#define LEAF_START 4095
#define HSTR 152
#define UC 768            // Ut2 padded cols (750 used)
#define WC 456            // Wt2 padded cols (450 used)
#define BLK 256
#define NTILES 2178
#define NCNT 2049

// indexed by level d = 0(root) .. 11
__device__ __constant__ int tileOff_[12] = {2176,2174,2172,2168,2160,2144,2112,2048,1920,1792,1536,1024};
__device__ __constant__ int ntl_[12]     = {1,1,1,2,4,8,16,32,64,128,256,512};   // node-tiles per level
__device__ __constant__ int hsl_[12]     = {2,2,2,2,2,2,2,2,2,1,1,1};
__device__ __constant__ int NBt_[12]     = {1,2,4,4,4,4,4,4,4,4,4,4};
// cnt bases: idx 0..11 = level d, idx 12 = leaf tiles
__device__ __constant__ int cntBase_[13] = {2048,2047,2046,2044,2040,2032,2016,1984,1920,1792,1536,1024,0};

struct P {
    const float *Ut2, *Wt2, *ub, *wb, *Why, *by, *emb;
    const int *words, *lchs, *rchs, *scores;
    float *H, *C, *lossAcc, *out;
    int *cnt, *done;
};

struct Q {
    const float *Wi,*bi,*Wo,*bo,*Wu,*bu;
    const float *U0i,*U1i,*bbi,*U00f,*U01f,*U10f,*U11f,*bbf,*U0o,*U1o,*bbo,*U0u,*U1u,*bbu;
    float *Ut2,*Wt2,*ub,*wb;
    int *zeroI;
};

__device__ __forceinline__ float sigf(float x){ return 1.0f/(1.0f+__expf(-x)); }
__device__ __forceinline__ float aloadf(const float* p){ return __hip_atomic_load(p, __ATOMIC_RELAXED, __HIP_MEMORY_SCOPE_AGENT); }
__device__ __forceinline__ void astoref(float* p, float v){ __hip_atomic_store(p, v, __ATOMIC_RELAXED, __HIP_MEMORY_SCOPE_AGENT); }
__device__ __forceinline__ int aloadi(const int* p){ return __hip_atomic_load(p, __ATOMIC_RELAXED, __HIP_MEMORY_SCOPE_AGENT); }

// ---------------- prep ----------------
__global__ __launch_bounds__(256) void prep(Q q)
{
    const long stride = (long)gridDim.x * 256;
    const long g0 = (long)blockIdx.x * 256 + threadIdx.x;
    for (long i = g0; i < 300L*UC; i += stride) {
        int k = (int)(i / UC), j = (int)(i - (long)k*UC); float v = 0.f;
        if (j < 750) {
            int g = j / 150, h = j - g*150; bool L = (k < HID); int kk = L ? k : k - HID;
            const float* U = (g==0) ? (L?q.U0i:q.U1i) : (g==1) ? (L?q.U00f:q.U01f) :
                             (g==2) ? (L?q.U10f:q.U11f) : (g==3) ? (L?q.U0o:q.U1o) : (L?q.U0u:q.U1u);
            v = U[h*HID + kk];
        }
        q.Ut2[i] = v;
    }
    for (long i = g0; i < 300L*WC; i += stride) {
        int k = (int)(i / WC), j = (int)(i - (long)k*WC); float v = 0.f;
        if (j < 450) {
            int g = j / 150, h = j - g*150;
            const float* W = (g==0) ? q.Wi : (g==1) ? q.Wo : q.Wu;
            v = W[h*EMB + k];
        }
        q.Wt2[i] = v;
    }
    for (long i = g0; i < UC; i += stride) {
        float v = 0.f;
        if (i < 750) { int g = (int)i/150, h = (int)i%150;
            const float* b = (g==0)?q.bbi:(g==1||g==2)?q.bbf:(g==3)?q.bbo:q.bbu; v = b[h]; }
        q.ub[i] = v;
    }
    for (long i = g0; i < WC; i += stride) {
        float v = 0.f;
        if (i < 450) { int g = (int)i/150, h = (int)i%150;
            const float* b = (g==0)?q.bi:(g==1)?q.bo:q.bu; v = b[h]; }
        q.wb[i] = v;
    }
    for (long i = g0; i < NCNT + 2; i += stride) q.zeroI[i] = 0;  // cnt + done + lossAcc
}

// ---------------- fused dataflow kernel ----------------
__global__ __launch_bounds__(BLK, 8) void tree_fused(P p)
{
    __shared__ __align__(16) float Xs[1200];   // x tile [k][4]  (also loss stash for hs2)
    __shared__ __align__(16) float Gs[3040];   // pre-activations / partials
    __shared__ float Ls[20];
    __shared__ float Lm[4];
    __shared__ int sw[4];
    __shared__ int flagS;

    const int tid = threadIdx.x;

    for (int t = blockIdx.x; t < NTILES; t += gridDim.x) {
        if (t < 1024) {
            // ================= leaf tile: 4 leaves, 450 cols, c=2 =================
            const int nodeBase = LEAF_START + t*4;
            if (tid < 4) sw[tid] = p.words[nodeBase + tid];
            __syncthreads();
            for (int idx = tid; idx < 1200; idx += BLK) {
                int m = idx / 300, k = idx - m*300;
                Xs[k*4 + m] = p.emb[(long)sw[m]*EMB + k];
            }
            __syncthreads();
            if (tid < 225) {
                float acc[4][2];
#pragma unroll
                for (int m = 0; m < 4; ++m) { acc[m][0]=0.f; acc[m][1]=0.f; }
                const float* wp = p.Wt2 + tid;
#pragma unroll 4
                for (int k = 0; k < 300; ++k) {
                    const float* wr = wp + (long)k*WC;
                    float w0 = wr[0], w1 = wr[225];
                    float4 x = *(const float4*)&Xs[k*4];
                    acc[0][0]=fmaf(x.x,w0,acc[0][0]); acc[0][1]=fmaf(x.x,w1,acc[0][1]);
                    acc[1][0]=fmaf(x.y,w0,acc[1][0]); acc[1][1]=fmaf(x.y,w1,acc[1][1]);
                    acc[2][0]=fmaf(x.z,w0,acc[2][0]); acc[2][1]=fmaf(x.z,w1,acc[2][1]);
                    acc[3][0]=fmaf(x.w,w0,acc[3][0]); acc[3][1]=fmaf(x.w,w1,acc[3][1]);
                }
#pragma unroll
                for (int m = 0; m < 4; ++m) {
                    Gs[m*452 + tid] = acc[m][0];
                    Gs[m*452 + 225 + tid] = acc[m][1];
                }
            }
            __syncthreads();
            for (int idx = tid; idx < 600; idx += BLK) {
                int m = idx / 150, h = idx - m*150;
                float ig = sigf(Gs[m*452 + h]        + p.wb[h]);
                float og = sigf(Gs[m*452 + 150 + h]  + p.wb[150+h]);
                float uv = tanhf(Gs[m*452 + 300 + h] + p.wb[300+h]);
                float c  = ig * uv;
                float hv = og * tanhf(c);
                long node = nodeBase + m;
                astoref(&p.H[node*HSTR + h], hv);
                astoref(&p.C[node*HSTR + h], c);
                Gs[m*452 + h] = hv;   // stash for loss (own-slot, safe)
            }
            __syncthreads();
            if (tid == 0) atomicAdd(&p.cnt[t], 1);   // leaf counter = tile index
            // loss for 4 leaves from Gs stash
            if (tid < 20) {
                int g = tid / 4, m = tid & 3;
                float l = p.by[g];
                const float* wy = p.Why + g*HID;
                for (int h = 0; h < HID; ++h) l = fmaf(wy[h], Gs[m*452 + h], l);
                Ls[g*4 + m] = l;
            }
            __syncthreads();
            if (tid < 4) {
                float l0=Ls[tid],l1=Ls[4+tid],l2=Ls[8+tid],l3=Ls[12+tid],l4=Ls[16+tid];
                float mx = fmaxf(fmaxf(fmaxf(l0,l1),fmaxf(l2,l3)),l4);
                float se = __expf(l0-mx)+__expf(l1-mx)+__expf(l2-mx)+__expf(l3-mx)+__expf(l4-mx);
                float lse = mx + __logf(se);
                int sc = p.scores[nodeBase + tid];
                float lsc = (sc==0)?l0:(sc==1)?l1:(sc==2)?l2:(sc==3)?l3:l4;
                Lm[tid] = lse - lsc;
            }
            __syncthreads();
            if (tid == 0) atomicAdd(p.lossAcc, Lm[0]+Lm[1]+Lm[2]+Lm[3]);
            __syncthreads();
        } else {
            // ================= internal tile =================
            int d;
            for (d = 11; d >= 0; --d) {
                int off = tileOff_[d];
                if (t >= off && t - off < ntl_[d]*hsl_[d]) break;
            }
            const int idx2 = t - tileOff_[d];
            const int hs = hsl_[d], NB = NBt_[d];
            const int nt  = (hs == 2) ? (idx2 >> 1) : idx2;
            const int hsi = (hs == 2) ? (idx2 & 1) : 0;
            const int n0 = (1 << d) - 1 + nt*4;   // compute always 4 (clamped); real nodes n0..n0+NB-1

            // dependencies
            const int NBc = (d == 0) ? 2 : 4;
            const int cb  = cntBase_[d+1];
            const int ct0 = (2*nt*NB) / NBc;
            int nchild = (2*NB) / NBc; if (nchild < 1) nchild = 1;
            const int needHs = (d <= 7) ? 2 : 1;
            if (tid < nchild)
                while (aloadi(&p.cnt[cb + ct0 + tid]) < needHs) __builtin_amdgcn_s_sleep(4);
            __syncthreads();

            // stage x = [lh||rh] for 4 nodes (children rows are contiguous: 2*n+1, 2*n+2)
            for (int idx = tid; idx < 1200; idx += BLK) {
                int m = idx / 300, k = idx - m*300;
                int mm = (m < NB) ? m : 0;
                long row = 2L*(n0 + mm) + 1 + (k >= 150 ? 1 : 0);
                int kk = (k >= 150) ? k - 150 : k;
                Xs[k*4 + m] = aloadf(&p.H[row*HSTR + kk]);
            }
            __syncthreads();

            if (d >= 9) {
                // ---- heavy path: 250 threads x 3 cols, full K ----
                if (tid < 250) {
                    float acc[4][3];
#pragma unroll
                    for (int m = 0; m < 4; ++m) { acc[m][0]=0.f; acc[m][1]=0.f; acc[m][2]=0.f; }
                    const float* wp = p.Ut2 + tid;
#pragma unroll 4
                    for (int k = 0; k < 300; ++k) {
                        const float* wr = wp + (long)k*UC;
                        float w0 = wr[0], w1 = wr[250], w2 = wr[500];
                        float4 x = *(const float4*)&Xs[k*4];
                        acc[0][0]=fmaf(x.x,w0,acc[0][0]); acc[0][1]=fmaf(x.x,w1,acc[0][1]); acc[0][2]=fmaf(x.x,w2,acc[0][2]);
                        acc[1][0]=fmaf(x.y,w0,acc[1][0]); acc[1][1]=fmaf(x.y,w1,acc[1][1]); acc[1][2]=fmaf(x.y,w2,acc[1][2]);
                        acc[2][0]=fmaf(x.z,w0,acc[2][0]); acc[2][1]=fmaf(x.z,w1,acc[2][1]); acc[2][2]=fmaf(x.z,w2,acc[2][2]);
                        acc[3][0]=fmaf(x.w,w0,acc[3][0]); acc[3][1]=fmaf(x.w,w1,acc[3][1]); acc[3][2]=fmaf(x.w,w2,acc[3][2]);
                    }
#pragma unroll
                    for (int m = 0; m < 4; ++m) {
                        Gs[m*752 + tid]       = acc[m][0];
                        Gs[m*752 + 250 + tid] = acc[m][1];
                        Gs[m*752 + 500 + tid] = acc[m][2];
                    }
                }
                __syncthreads();
                for (int idx = tid; idx < 600; idx += BLK) {
                    int m = idx / 150, h = idx - m*150;
                    float ig = sigf (Gs[m*752 + h]       + p.ub[h]);
                    float fl = sigf (Gs[m*752 + 150 + h] + p.ub[150+h]);
                    float fr = sigf (Gs[m*752 + 300 + h] + p.ub[300+h]);
                    float og = sigf (Gs[m*752 + 450 + h] + p.ub[450+h]);
                    float uv = tanhf(Gs[m*752 + 600 + h] + p.ub[600+h]);
                    long lrow = 2L*(n0+m) + 1, rrow = lrow + 1;
                    float lc = aloadf(&p.C[lrow*HSTR + h]);
                    float rc = aloadf(&p.C[rrow*HSTR + h]);
                    float c  = ig*uv + fl*lc + fr*rc;
                    float hv = og * tanhf(c);
                    long node = n0 + m;
                    astoref(&p.H[node*HSTR + h], hv);
                    astoref(&p.C[node*HSTR + h], c);
                    Gs[m*752 + h] = hv;
                }
                __syncthreads();
                if (tid == 0) atomicAdd(&p.cnt[cntBase_[d] + nt], 1);
                // loss for 4 nodes from Gs stash
                if (tid < 20) {
                    int g = tid / 4, m = tid & 3;
                    float l = p.by[g];
                    const float* wy = p.Why + g*HID;
                    for (int h = 0; h < HID; ++h) l = fmaf(wy[h], Gs[m*752 + h], l);
                    Ls[g*4 + m] = l;
                }
                __syncthreads();
                if (tid < 4) {
                    float l0=Ls[tid],l1=Ls[4+tid],l2=Ls[8+tid],l3=Ls[12+tid],l4=Ls[16+tid];
                    float mx = fmaxf(fmaxf(fmaxf(l0,l1),fmaxf(l2,l3)),l4);
                    float se = __expf(l0-mx)+__expf(l1-mx)+__expf(l2-mx)+__expf(l3-mx)+__expf(l4-mx);
                    float lse = mx + __logf(se);
                    int sc = p.scores[n0 + tid];
                    float lsc = (sc==0)?l0:(sc==1)?l1:(sc==2)?l2:(sc==3)?l3:l4;
                    Lm[tid] = lse - lsc;
                }
                __syncthreads();
                if (tid == 0) atomicAdd(p.lossAcc, Lm[0]+Lm[1]+Lm[2]+Lm[3]);
                __syncthreads();
            } else {
                // ---- tail path: hs=2 (this block owns h-half hsi), intra-block ks=2 ----
                const int kseg = tid >> 7, j = tid & 127;
                if (j < 125) {
                    // 3 local cols: c' = j, j+125, j+250 of 375; global col = (c'/75)*150 + hsi*75 + c'%75
                    int off0, off1, off2;
                    {
                        int c0 = j,        g0 = c0/75, r0 = c0 - g0*75; off0 = g0*150 + hsi*75 + r0;
                        int c1 = j + 125,  g1 = c1/75, r1 = c1 - g1*75; off1 = g1*150 + hsi*75 + r1;
                        int c2 = j + 250,  g2 = c2/75, r2 = c2 - g2*75; off2 = g2*150 + hsi*75 + r2;
                    }
                    float acc[4][3];
#pragma unroll
                    for (int m = 0; m < 4; ++m) { acc[m][0]=0.f; acc[m][1]=0.f; acc[m][2]=0.f; }
                    const int k0 = kseg * 150;
#pragma unroll 4
                    for (int k = k0; k < k0 + 150; ++k) {
                        const float* wr = p.Ut2 + (long)k*UC;
                        float w0 = wr[off0], w1 = wr[off1], w2 = wr[off2];
                        float4 x = *(const float4*)&Xs[k*4];
                        acc[0][0]=fmaf(x.x,w0,acc[0][0]); acc[0][1]=fmaf(x.x,w1,acc[0][1]); acc[0][2]=fmaf(x.x,w2,acc[0][2]);
                        acc[1][0]=fmaf(x.y,w0,acc[1][0]); acc[1][1]=fmaf(x.y,w1,acc[1][1]); acc[1][2]=fmaf(x.y,w2,acc[1][2]);
                        acc[2][0]=fmaf(x.z,w0,acc[2][0]); acc[2][1]=fmaf(x.z,w1,acc[2][1]); acc[2][2]=fmaf(x.z,w2,acc[2][2]);
                        acc[3][0]=fmaf(x.w,w0,acc[3][0]); acc[3][1]=fmaf(x.w,w1,acc[3][1]); acc[3][2]=fmaf(x.w,w2,acc[3][2]);
                    }
#pragma unroll
                    for (int m = 0; m < 4; ++m) {
                        Gs[(kseg*4 + m)*380 + j]       = acc[m][0];
                        Gs[(kseg*4 + m)*380 + 125 + j] = acc[m][1];
                        Gs[(kseg*4 + m)*380 + 250 + j] = acc[m][2];
                    }
                }
                __syncthreads();
                for (int idx = tid; idx < NB*75; idx += BLK) {
                    int m = idx / 75, dh = idx - m*75;
                    int h = hsi*75 + dh;
                    float pre[5];
#pragma unroll
                    for (int g = 0; g < 5; ++g)
                        pre[g] = Gs[m*380 + g*75 + dh] + Gs[(4+m)*380 + g*75 + dh];
                    float ig = sigf (pre[0] + p.ub[h]);
                    float fl = sigf (pre[1] + p.ub[150+h]);
                    float fr = sigf (pre[2] + p.ub[300+h]);
                    float og = sigf (pre[3] + p.ub[450+h]);
                    float uv = tanhf(pre[4] + p.ub[600+h]);
                    long lrow = 2L*(n0+m) + 1, rrow = lrow + 1;
                    float lc = aloadf(&p.C[lrow*HSTR + h]);
                    float rc = aloadf(&p.C[rrow*HSTR + h]);
                    float c  = ig*uv + fl*lc + fr*rc;
                    float hv = og * tanhf(c);
                    long node = n0 + m;
                    astoref(&p.H[node*HSTR + h], hv);
                    astoref(&p.C[node*HSTR + h], c);
                }
                __syncthreads();
                if (tid == 0) {
                    int old = atomicAdd(&p.cnt[cntBase_[d] + nt], 1);
                    flagS = (old == 1);   // last h-half does the loss
                }
                __syncthreads();
                if (flagS) {
                    for (int idx = tid; idx < NB*150; idx += BLK) {
                        int m = idx / 150, h = idx - m*150;
                        Xs[m*152 + h] = aloadf(&p.H[(long)(n0+m)*HSTR + h]);
                    }
                    __syncthreads();
                    if (tid < 5*NB) {
                        int g = tid / NB, m = tid - g*NB;
                        float l = p.by[g];
                        const float* wy = p.Why + g*HID;
                        for (int h = 0; h < HID; ++h) l = fmaf(wy[h], Xs[m*152 + h], l);
                        Ls[g*4 + m] = l;
                    }
                    __syncthreads();
                    if (tid < NB) {
                        float l0=Ls[tid],l1=Ls[4+tid],l2=Ls[8+tid],l3=Ls[12+tid],l4=Ls[16+tid];
                        float mx = fmaxf(fmaxf(fmaxf(l0,l1),fmaxf(l2,l3)),l4);
                        float se = __expf(l0-mx)+__expf(l1-mx)+__expf(l2-mx)+__expf(l3-mx)+__expf(l4-mx);
                        float lse = mx + __logf(se);
                        int sc = p.scores[n0 + tid];
                        float lsc = (sc==0)?l0:(sc==1)?l1:(sc==2)?l2:(sc==3)?l3:l4;
                        Lm[tid] = lse - lsc;
                    }
                    __syncthreads();
                    if (tid == 0) {
                        float s = 0.f;
                        for (int m = 0; m < NB; ++m) s += Lm[m];
                        atomicAdd(p.lossAcc, s);
                    }
                }
                __syncthreads();
            }
        }
    }

    if (tid == 0) {
        __threadfence();
        int old = atomicAdd(p.done, 1);
        if (old == (int)gridDim.x - 1) p.out[0] = aloadf(p.lossAcc);
    }
}

extern "C" void kernel_launch(void* const* d_in, const int* in_sizes, int n_in,
                              void* d_out, int out_size, void* d_ws, size_t ws_size,
                              hipStream_t stream)
{
    float* ws = (float*)d_ws;
    float* Ut2 = ws;                      // 300*768
    float* Wt2 = Ut2 + 300*UC;            // 300*456
    float* ub  = Wt2 + 300*WC;            // 768
    float* wb  = ub + UC;                 // 456
    float* H   = wb + WC;                 // 8191*152
    float* C   = H + (long)NNODES*HSTR;
    float* tail = C + (long)NNODES*HSTR;
    int*   cnt = (int*)tail;              // NCNT
    int*   done = cnt + NCNT;
    float* lossAcc = (float*)(cnt + NCNT + 1);

    Q q;
    q.Wi  = (const float*)d_in[0];  q.bi  = (const float*)d_in[1];
    q.Wo  = (const float*)d_in[2];  q.bo  = (const float*)d_in[3];
    q.Wu  = (const float*)d_in[4];  q.bu  = (const float*)d_in[5];
    q.U0i = (const float*)d_in[6];  q.U1i = (const float*)d_in[7];
    q.bbi = (const float*)d_in[8];
    q.U00f= (const float*)d_in[9];  q.U01f= (const float*)d_in[10];
    q.U10f= (const float*)d_in[11]; q.U11f= (const float*)d_in[12];
    q.bbf = (const float*)d_in[13];
    q.U0o = (const float*)d_in[14]; q.U1o = (const float*)d_in[15];
    q.bbo = (const float*)d_in[16];
    q.U0u = (const float*)d_in[17]; q.U1u = (const float*)d_in[18];
    q.bbu = (const float*)d_in[19];
    q.Ut2 = Ut2; q.Wt2 = Wt2; q.ub = ub; q.wb = wb; q.zeroI = cnt;

    P p;
    p.Ut2 = Ut2; p.Wt2 = Wt2; p.ub = ub; p.wb = wb;
    p.Why = (const float*)d_in[20]; p.by = (const float*)d_in[21];
    p.emb = (const float*)d_in[22];
    p.scores = (const int*)d_in[23]; p.words = (const int*)d_in[24];
    p.lchs = (const int*)d_in[25];   p.rchs = (const int*)d_in[26];
    p.H = H; p.C = C; p.lossAcc = lossAcc; p.out = (float*)d_out;
    p.cnt = cnt; p.done = done;

    hipLaunchKernelGGL(prep, dim3(512), dim3(256), 0, stream, q);

    int maxB = 0;
    hipOccupancyMaxActiveBlocksPerMultiprocessor(&maxB, tree_fused, BLK, 0);
    if (maxB < 1) maxB = 1;
    long G = (long)maxB * 256;
    if (G > 2048) G = 2048;

    void* kargs[] = { (void*)&p };
    hipLaunchCooperativeKernel((void*)tree_fused, dim3((int)G), dim3(BLK), kargs, 0, stream);
}